// Round 2
// baseline (395.016 us; speedup 1.0000x reference)
//
#include <hip/hip_runtime.h>
#include <hip/hip_bf16.h>

typedef __bf16 bf16x8_t __attribute__((ext_vector_type(8)));
typedef float f32x4_t __attribute__((ext_vector_type(4)));

static __device__ __forceinline__ float bf2f(unsigned short u) {
    union { unsigned int i; float f; } z; z.i = ((unsigned int)u) << 16; return z.f;
}

// ---------------------------------------------------------------- cast kernel
__global__ __launch_bounds__(256) void cast_bf16_all(
    const float* __restrict__ x, const float* __restrict__ h,
    const float* __restrict__ wi, const float* __restrict__ wh,
    __hip_bfloat16* __restrict__ xb, __hip_bfloat16* __restrict__ hb,
    __hip_bfloat16* __restrict__ wib, __hip_bfloat16* __restrict__ whb)
{
    const size_t CX = (size_t)8192 * 1024 / 8;   // 1048576 chunks of 8
    const size_t CW = (size_t)4096 * 1024 / 8;   // 524288
    const size_t TOT = CX * 2 + CW * 2;          // 3145728
    for (size_t cp = (size_t)blockIdx.x * blockDim.x + threadIdx.x; cp < TOT;
         cp += (size_t)gridDim.x * blockDim.x) {
        const float* src; __hip_bfloat16* dst; size_t off;
        if (cp < CX)            { src = x;  dst = xb;  off = cp; }
        else if (cp < 2 * CX)   { src = h;  dst = hb;  off = cp - CX; }
        else if (cp < 2*CX+CW)  { src = wi; dst = wib; off = cp - 2 * CX; }
        else                    { src = wh; dst = whb; off = cp - 2 * CX - CW; }
        const float4* s4 = (const float4*)src;
        float4 a = s4[off * 2], b = s4[off * 2 + 1];
        union { __hip_bfloat16 q[8]; uint4 u; } pk;
        pk.q[0] = __float2bfloat16(a.x); pk.q[1] = __float2bfloat16(a.y);
        pk.q[2] = __float2bfloat16(a.z); pk.q[3] = __float2bfloat16(a.w);
        pk.q[4] = __float2bfloat16(b.x); pk.q[5] = __float2bfloat16(b.y);
        pk.q[6] = __float2bfloat16(b.z); pk.q[7] = __float2bfloat16(b.w);
        ((uint4*)dst)[off] = pk.u;
    }
}

// ------------------------------------------------------------- 128x128 GEMM
// P[m,n] = sum_k A[m,k] * W[n,k]   (A: MxK row-major, W: NxK row-major)
// M=8192, N=4096, K=1024.  blockIdx.z selects (x,w_ih,pre_ih) vs (h,w_hh,pre_hh)
__global__ __launch_bounds__(256) void gemm_bt128(
    const __hip_bfloat16* __restrict__ Ax, const __hip_bfloat16* __restrict__ Ah,
    const __hip_bfloat16* __restrict__ Wi, const __hip_bfloat16* __restrict__ Wh,
    __hip_bfloat16* __restrict__ Pi, __hip_bfloat16* __restrict__ Ph)
{
    const int K = 1024, N = 4096;
    const __hip_bfloat16* A; const __hip_bfloat16* W; __hip_bfloat16* P;
    if (blockIdx.z == 0) { A = Ax; W = Wi; P = Pi; }
    else                 { A = Ah; W = Wh; P = Ph; }
    const int n0 = blockIdx.x * 128, m0 = blockIdx.y * 128;

    __shared__ __align__(16) __hip_bfloat16 lsA[128 * 32];
    __shared__ __align__(16) __hip_bfloat16 lsB[128 * 32];

    const int t = threadIdx.x, w = t >> 6, l = t & 63;
    const int wr = w >> 1, wc = w & 1;
    const int lrow = l & 15, lk = (l >> 4) * 8;

    f32x4_t acc[4][4];
    #pragma unroll
    for (int mi = 0; mi < 4; ++mi)
        #pragma unroll
        for (int ni = 0; ni < 4; ++ni)
            acc[mi][ni] = (f32x4_t){0.f, 0.f, 0.f, 0.f};

    for (int kt = 0; kt < K / 32; ++kt) {
        // stage 128x32 A-tile and 128x32 W-tile: 512 x 16B each, 2 rounds of 256 thr
        #pragma unroll
        for (int s = 0; s < 2; ++s) {
            const int idx = s * 256 + t;
            const int row = idx >> 2;             // 0..127
            const int kk  = (idx & 3) * 8;        // 0,8,16,24
            const __hip_bfloat16* ga = A + (size_t)(m0 + row) * K + kt * 32 + kk;
            const __hip_bfloat16* gb = W + (size_t)(n0 + row) * K + kt * 32 + kk;
            // LDS dest is wave-uniform base + lane*16B  (linear layout)
            __builtin_amdgcn_global_load_lds(
                (const __attribute__((address_space(1))) void*)ga,
                (__attribute__((address_space(3))) void*)&lsA[(s * 256 + w * 64) * 8],
                16, 0, 0);
            __builtin_amdgcn_global_load_lds(
                (const __attribute__((address_space(1))) void*)gb,
                (__attribute__((address_space(3))) void*)&lsB[(s * 256 + w * 64) * 8],
                16, 0, 0);
        }
        __syncthreads();   // drains vmcnt before any LDS read

        bf16x8_t af[4], bfv[4];
        #pragma unroll
        for (int mi = 0; mi < 4; ++mi)
            af[mi] = *(const bf16x8_t*)&lsA[(wr * 64 + mi * 16 + lrow) * 32 + lk];
        #pragma unroll
        for (int ni = 0; ni < 4; ++ni)
            bfv[ni] = *(const bf16x8_t*)&lsB[(wc * 64 + ni * 16 + lrow) * 32 + lk];
        #pragma unroll
        for (int mi = 0; mi < 4; ++mi)
            #pragma unroll
            for (int ni = 0; ni < 4; ++ni)
                acc[mi][ni] = __builtin_amdgcn_mfma_f32_16x16x32_bf16(
                    af[mi], bfv[ni], acc[mi][ni], 0, 0, 0);
        __syncthreads();   // LDS reads done before next stage overwrites
    }

    // epilogue: C/D layout col=l&15, row=(l>>4)*4+q  (verified m89/m91)
    #pragma unroll
    for (int mi = 0; mi < 4; ++mi) {
        #pragma unroll
        for (int ni = 0; ni < 4; ++ni) {
            const int cc = n0 + wc * 64 + ni * 16 + (l & 15);
            #pragma unroll
            for (int q = 0; q < 4; ++q) {
                const int r = m0 + wr * 64 + mi * 16 + (l >> 4) * 4 + q;
                P[(size_t)r * N + cc] = __float2bfloat16(acc[mi][ni][q]);
            }
        }
    }
}

// ------------------------------------------------- fused LN + gates kernel
__device__ __forceinline__ void blockReduce2(float& a, float& b, float* red, int t) {
    #pragma unroll
    for (int o = 32; o > 0; o >>= 1) { a += __shfl_down(a, o); b += __shfl_down(b, o); }
    __syncthreads();                       // previous users of red[] are done
    if ((t & 63) == 0) { red[(t >> 6) * 2] = a; red[(t >> 6) * 2 + 1] = b; }
    __syncthreads();
    a = red[0] + red[2] + red[4] + red[6];
    b = red[1] + red[3] + red[5] + red[7];
}

__global__ __launch_bounds__(256) void lstm_fuse(
    const __hip_bfloat16* __restrict__ pih, const __hip_bfloat16* __restrict__ phh,
    const float* __restrict__ c, const float* __restrict__ bih,
    const float* __restrict__ gamma, const float* __restrict__ beta,
    float* __restrict__ out)
{
    const int H = 1024;
    const size_t BH = (size_t)8192 * 1024;
    const int b = blockIdx.x, t = threadIdx.x;
    __shared__ float red[8];

    const ushort* pi = (const ushort*)(pih + (size_t)b * 4096);
    const ushort* ph = (const ushort*)(phh + (size_t)b * 4096);

    float v[8][4], mu[8], rs[8];
    // segments s = gate*2 + src (src 0 = ih, 1 = hh); gamma/beta row = s
    #pragma unroll
    for (int s = 0; s < 8; ++s) {
        const ushort* src = ((s & 1) ? ph : pi) + (s >> 1) * H + t * 4;
        ushort4 u = *(const ushort4*)src;
        v[s][0] = bf2f(u.x); v[s][1] = bf2f(u.y);
        v[s][2] = bf2f(u.z); v[s][3] = bf2f(u.w);
        float sm = v[s][0] + v[s][1] + v[s][2] + v[s][3];
        float sq = v[s][0]*v[s][0] + v[s][1]*v[s][1] + v[s][2]*v[s][2] + v[s][3]*v[s][3];
        blockReduce2(sm, sq, red, t);
        mu[s] = sm * (1.f / H);
        rs[s] = rsqrtf(sq * (1.f / H) - mu[s] * mu[s] + 1e-5f);
    }

    float4 cv4 = *(const float4*)(c + (size_t)b * H + t * 4);
    float cvv[4] = {cv4.x, cv4.y, cv4.z, cv4.w};
    float ov[4], cn[4];
    float s9 = 0.f, q9 = 0.f;
    #pragma unroll
    for (int q = 0; q < 4; ++q) {
        const int j = t * 4 + q;
        float n[4];
        #pragma unroll
        for (int g = 0; g < 4; ++g) {
            const int si = g * 2, sh = g * 2 + 1;
            float a_ = (v[si][q] - mu[si]) * rs[si] * gamma[si * H + j] + beta[si * H + j];
            float h_ = (v[sh][q] - mu[sh]) * rs[sh] * gamma[sh * H + j] + beta[sh * H + j];
            n[g] = a_ + h_ + bih[g * H + j];
        }
        const float ig = 1.f / (1.f + __expf(-n[0]));
        const float fg = 1.f / (1.f + __expf(-n[1]));
        const float ag = tanhf(n[2]);
        const float og = 1.f / (1.f + __expf(-n[3]));
        cn[q] = fg * cvv[q] + ig * ag;
        ov[q] = og;
        s9 += cn[q]; q9 += cn[q] * cn[q];
    }
    blockReduce2(s9, q9, red, t);
    const float mu9 = s9 * (1.f / H);
    const float rs9 = rsqrtf(q9 * (1.f / H) - mu9 * mu9 + 1e-5f);

    float4 hn4, cn4;
    float hn[4];
    #pragma unroll
    for (int q = 0; q < 4; ++q) {
        const int j = t * 4 + q;
        hn[q] = ov[q] * tanhf((cn[q] - mu9) * rs9 * gamma[8 * H + j] + beta[8 * H + j]);
    }
    hn4.x = hn[0]; hn4.y = hn[1]; hn4.z = hn[2]; hn4.w = hn[3];
    cn4.x = cn[0]; cn4.y = cn[1]; cn4.z = cn[2]; cn4.w = cn[3];
    *(float4*)(out + (size_t)b * H + t * 4) = hn4;
    *(float4*)(out + BH + (size_t)b * H + t * 4) = cn4;
}

// ----------------------------------------------------------------- launcher
extern "C" void kernel_launch(void* const* d_in, const int* in_sizes, int n_in,
                              void* d_out, int out_size, void* d_ws, size_t ws_size,
                              hipStream_t stream) {
    const float* x     = (const float*)d_in[0];
    const float* h     = (const float*)d_in[1];
    const float* c     = (const float*)d_in[2];
    const float* w_ih  = (const float*)d_in[3];
    const float* w_hh  = (const float*)d_in[4];
    const float* b_ih  = (const float*)d_in[5];
    const float* gamma = (const float*)d_in[6];
    const float* beta  = (const float*)d_in[7];
    float* out = (float*)d_out;

    char* ws = (char*)d_ws;
    __hip_bfloat16* xb  = (__hip_bfloat16*)(ws);                      // 16 MB
    __hip_bfloat16* hb  = (__hip_bfloat16*)(ws + ((size_t)16 << 20)); // 16 MB
    __hip_bfloat16* wib = (__hip_bfloat16*)(ws + ((size_t)32 << 20)); //  8 MB
    __hip_bfloat16* whb = (__hip_bfloat16*)(ws + ((size_t)40 << 20)); //  8 MB
    __hip_bfloat16* pih = (__hip_bfloat16*)(ws + ((size_t)48 << 20)); // 64 MB
    __hip_bfloat16* phh = (__hip_bfloat16*)(ws + ((size_t)112 << 20));// 64 MB -> 176 MB total

    hipLaunchKernelGGL(cast_bf16_all, dim3(4096), dim3(256), 0, stream,
                       x, h, w_ih, w_hh, xb, hb, wib, whb);
    hipLaunchKernelGGL(gemm_bt128, dim3(4096 / 128, 8192 / 128, 2), dim3(256), 0, stream,
                       xb, hb, wib, whb, pih, phh);
    hipLaunchKernelGGL(lstm_fuse, dim3(8192), dim3(256), 0, stream,
                       pih, phh, c, b_ih, gamma, beta, out);
}

// Round 4
// 264.257 us; speedup vs baseline: 1.4948x; 1.4948x over previous
//
#include <hip/hip_runtime.h>
#include <hip/hip_bf16.h>

typedef __bf16 bf16x8_t __attribute__((ext_vector_type(8)));
typedef float f32x4_t __attribute__((ext_vector_type(4)));

static __device__ __forceinline__ float bf2f(unsigned short u) {
    union { unsigned int i; float f; } z; z.i = ((unsigned int)u) << 16; return z.f;
}

// ---------------------------------------------------------------- cast kernel
__global__ __launch_bounds__(256) void cast_bf16_all(
    const float* __restrict__ x, const float* __restrict__ h,
    const float* __restrict__ wi, const float* __restrict__ wh,
    __hip_bfloat16* __restrict__ xb, __hip_bfloat16* __restrict__ hb,
    __hip_bfloat16* __restrict__ wib, __hip_bfloat16* __restrict__ whb)
{
    const size_t CX = (size_t)8192 * 1024 / 8;   // 1048576 chunks of 8
    const size_t CW = (size_t)4096 * 1024 / 8;   // 524288
    const size_t TOT = CX * 2 + CW * 2;          // 3145728
    for (size_t cp = (size_t)blockIdx.x * blockDim.x + threadIdx.x; cp < TOT;
         cp += (size_t)gridDim.x * blockDim.x) {
        const float* src; __hip_bfloat16* dst; size_t off;
        if (cp < CX)            { src = x;  dst = xb;  off = cp; }
        else if (cp < 2 * CX)   { src = h;  dst = hb;  off = cp - CX; }
        else if (cp < 2*CX+CW)  { src = wi; dst = wib; off = cp - 2 * CX; }
        else                    { src = wh; dst = whb; off = cp - 2 * CX - CW; }
        const float4* s4 = (const float4*)src;
        float4 a = s4[off * 2], b = s4[off * 2 + 1];
        union { __hip_bfloat16 q[8]; uint4 u; } pk;
        pk.q[0] = __float2bfloat16(a.x); pk.q[1] = __float2bfloat16(a.y);
        pk.q[2] = __float2bfloat16(a.z); pk.q[3] = __float2bfloat16(a.w);
        pk.q[4] = __float2bfloat16(b.x); pk.q[5] = __float2bfloat16(b.y);
        pk.q[6] = __float2bfloat16(b.z); pk.q[7] = __float2bfloat16(b.w);
        ((uint4*)dst)[off] = pk.u;
    }
}

// ------------------------------------------------------------- 128x128 GEMM
// P[m,n] = sum_k A[m,k] * W[n,k]   (A: MxK row-major, W: NxK row-major)
__global__ __launch_bounds__(256) void gemm_bt128(
    const __hip_bfloat16* __restrict__ Ax, const __hip_bfloat16* __restrict__ Ah,
    const __hip_bfloat16* __restrict__ Wi, const __hip_bfloat16* __restrict__ Wh,
    __hip_bfloat16* __restrict__ Pi, __hip_bfloat16* __restrict__ Ph)
{
    const int K = 1024, N = 4096;
    const __hip_bfloat16* A; const __hip_bfloat16* W; __hip_bfloat16* P;
    if (blockIdx.z == 0) { A = Ax; W = Wi; P = Pi; }
    else                 { A = Ah; W = Wh; P = Ph; }
    const int n0 = blockIdx.x * 128, m0 = blockIdx.y * 128;

    __shared__ __align__(16) __hip_bfloat16 lsA[128 * 32];
    __shared__ __align__(16) __hip_bfloat16 lsB[128 * 32];

    const int t = threadIdx.x, w = t >> 6, l = t & 63;
    const int wr = w >> 1, wc = w & 1;
    const int lrow = l & 15, lk = (l >> 4) * 8;

    f32x4_t acc[4][4];
    #pragma unroll
    for (int mi = 0; mi < 4; ++mi)
        #pragma unroll
        for (int ni = 0; ni < 4; ++ni)
            acc[mi][ni] = (f32x4_t){0.f, 0.f, 0.f, 0.f};

    for (int kt = 0; kt < K / 32; ++kt) {
        #pragma unroll
        for (int s = 0; s < 2; ++s) {
            const int idx = s * 256 + t;
            const int row = idx >> 2;
            const int kk  = (idx & 3) * 8;
            const __hip_bfloat16* ga = A + (size_t)(m0 + row) * K + kt * 32 + kk;
            const __hip_bfloat16* gb = W + (size_t)(n0 + row) * K + kt * 32 + kk;
            __builtin_amdgcn_global_load_lds(
                (const __attribute__((address_space(1))) void*)ga,
                (__attribute__((address_space(3))) void*)&lsA[(s * 256 + w * 64) * 8],
                16, 0, 0);
            __builtin_amdgcn_global_load_lds(
                (const __attribute__((address_space(1))) void*)gb,
                (__attribute__((address_space(3))) void*)&lsB[(s * 256 + w * 64) * 8],
                16, 0, 0);
        }
        __syncthreads();

        bf16x8_t af[4], bfv[4];
        #pragma unroll
        for (int mi = 0; mi < 4; ++mi)
            af[mi] = *(const bf16x8_t*)&lsA[(wr * 64 + mi * 16 + lrow) * 32 + lk];
        #pragma unroll
        for (int ni = 0; ni < 4; ++ni)
            bfv[ni] = *(const bf16x8_t*)&lsB[(wc * 64 + ni * 16 + lrow) * 32 + lk];
        #pragma unroll
        for (int mi = 0; mi < 4; ++mi)
            #pragma unroll
            for (int ni = 0; ni < 4; ++ni)
                acc[mi][ni] = __builtin_amdgcn_mfma_f32_16x16x32_bf16(
                    af[mi], bfv[ni], acc[mi][ni], 0, 0, 0);
        __syncthreads();
    }

    #pragma unroll
    for (int mi = 0; mi < 4; ++mi) {
        #pragma unroll
        for (int ni = 0; ni < 4; ++ni) {
            const int cc = n0 + wc * 64 + ni * 16 + (l & 15);
            #pragma unroll
            for (int q = 0; q < 4; ++q) {
                const int r = m0 + wr * 64 + mi * 16 + (l >> 4) * 4 + q;
                P[(size_t)r * N + cc] = __float2bfloat16(acc[mi][ni][q]);
            }
        }
    }
}

// ------------------------------------------------- fused LN + gates kernel
// One block (256 thr) per batch row. All 8 gate-LN reductions batched into ONE
// shuffle+LDS round (2 barriers); LN(c_new) adds 1 more. vs 18 barriers before.
__global__ __launch_bounds__(256) void lstm_fuse(
    const __hip_bfloat16* __restrict__ pih, const __hip_bfloat16* __restrict__ phh,
    const float* __restrict__ c, const float* __restrict__ bih,
    const float* __restrict__ gamma, const float* __restrict__ beta,
    float* __restrict__ out)
{
    const int H = 1024;
    const size_t BH = (size_t)8192 * 1024;
    const int b = blockIdx.x, t = threadIdx.x;
    const int wid = t >> 6, lane = t & 63;

    __shared__ float red1[4][16];   // per-wave partials: [wave][s*2 + {0=sum,1=sq}]
    __shared__ float fin1[16];      // final sums
    __shared__ float red2[8];       // c_new round: [wave*2 + {0,1}]

    const ushort* pi = (const ushort*)(pih + (size_t)b * 4096);
    const ushort* ph = (const ushort*)(phh + (size_t)b * 4096);

    // ---- load all 8 segments (raw bf16, 2 VGPR each), partial sums
    ushort4 u[8];
    float sm[8], sq[8];
    #pragma unroll
    for (int s = 0; s < 8; ++s) {
        const ushort* src = ((s & 1) ? ph : pi) + (s >> 1) * H + t * 4;
        u[s] = *(const ushort4*)src;
        float a0 = bf2f(u[s].x), a1 = bf2f(u[s].y), a2 = bf2f(u[s].z), a3 = bf2f(u[s].w);
        sm[s] = a0 + a1 + a2 + a3;
        sq[s] = a0*a0 + a1*a1 + a2*a2 + a3*a3;
    }
    // ---- one butterfly over all 16 partials (ILP across s)
    #pragma unroll
    for (int o = 32; o > 0; o >>= 1) {
        #pragma unroll
        for (int s = 0; s < 8; ++s) {
            sm[s] += __shfl_down(sm[s], o);
            sq[s] += __shfl_down(sq[s], o);
        }
    }
    if (lane == 0) {
        #pragma unroll
        for (int s = 0; s < 8; ++s) {
            red1[wid][s * 2]     = sm[s];
            red1[wid][s * 2 + 1] = sq[s];
        }
    }
    __syncthreads();
    if (t < 16) fin1[t] = red1[0][t] + red1[1][t] + red1[2][t] + red1[3][t];
    __syncthreads();

    float mu[8], rs[8];
    {
        float4 f0 = *(const float4*)&fin1[0],  f1 = *(const float4*)&fin1[4];
        float4 f2 = *(const float4*)&fin1[8],  f3 = *(const float4*)&fin1[12];
        float fv[16] = {f0.x,f0.y,f0.z,f0.w, f1.x,f1.y,f1.z,f1.w,
                        f2.x,f2.y,f2.z,f2.w, f3.x,f3.y,f3.z,f3.w};
        #pragma unroll
        for (int s = 0; s < 8; ++s) {
            mu[s] = fv[s * 2] * (1.f / H);
            rs[s] = rsqrtf(fv[s * 2 + 1] * (1.f / H) - mu[s] * mu[s] + 1e-5f);
        }
    }

    // ---- gates
    float n[4][4];
    #pragma unroll
    for (int g = 0; g < 4; ++g) {
        const int si = g * 2, sh = g * 2 + 1;
        float4 ga = *(const float4*)&gamma[si * H + t * 4];
        float4 ba = *(const float4*)&beta [si * H + t * 4];
        float4 gh = *(const float4*)&gamma[sh * H + t * 4];
        float4 bh = *(const float4*)&beta [sh * H + t * 4];
        float4 bi = *(const float4*)&bih  [g  * H + t * 4];
        const float gav[4] = {ga.x,ga.y,ga.z,ga.w}, bav[4] = {ba.x,ba.y,ba.z,ba.w};
        const float ghv[4] = {gh.x,gh.y,gh.z,gh.w}, bhv[4] = {bh.x,bh.y,bh.z,bh.w};
        const float biv[4] = {bi.x,bi.y,bi.z,bi.w};
        const ushort uiv[4] = {u[si].x, u[si].y, u[si].z, u[si].w};
        const ushort uhv[4] = {u[sh].x, u[sh].y, u[sh].z, u[sh].w};
        #pragma unroll
        for (int q = 0; q < 4; ++q) {
            float a_ = (bf2f(uiv[q]) - mu[si]) * rs[si] * gav[q] + bav[q];
            float h_ = (bf2f(uhv[q]) - mu[sh]) * rs[sh] * ghv[q] + bhv[q];
            n[g][q] = a_ + h_ + biv[q];
        }
    }

    float4 cv4 = *(const float4*)(c + (size_t)b * H + t * 4);
    const float cvv[4] = {cv4.x, cv4.y, cv4.z, cv4.w};
    float ov[4], cn[4];
    float s9 = 0.f, q9 = 0.f;
    #pragma unroll
    for (int q = 0; q < 4; ++q) {
        const float ig = 1.f / (1.f + __expf(-n[0][q]));
        const float fg = 1.f / (1.f + __expf(-n[1][q]));
        const float ag = tanhf(n[2][q]);
        const float og = 1.f / (1.f + __expf(-n[3][q]));
        cn[q] = fg * cvv[q] + ig * ag;
        ov[q] = og;
        s9 += cn[q]; q9 += cn[q] * cn[q];
    }
    #pragma unroll
    for (int o = 32; o > 0; o >>= 1) {
        s9 += __shfl_down(s9, o);
        q9 += __shfl_down(q9, o);
    }
    if (lane == 0) { red2[wid * 2] = s9; red2[wid * 2 + 1] = q9; }
    __syncthreads();
    const float S9 = red2[0] + red2[2] + red2[4] + red2[6];
    const float Q9 = red2[1] + red2[3] + red2[5] + red2[7];
    const float mu9 = S9 * (1.f / H);
    const float rs9 = rsqrtf(Q9 * (1.f / H) - mu9 * mu9 + 1e-5f);

    float4 g9 = *(const float4*)&gamma[8 * H + t * 4];
    float4 b9 = *(const float4*)&beta [8 * H + t * 4];
    const float g9v[4] = {g9.x,g9.y,g9.z,g9.w}, b9v[4] = {b9.x,b9.y,b9.z,b9.w};
    float4 hn4, cn4;
    float hn[4];
    #pragma unroll
    for (int q = 0; q < 4; ++q)
        hn[q] = ov[q] * tanhf((cn[q] - mu9) * rs9 * g9v[q] + b9v[q]);
    hn4.x = hn[0]; hn4.y = hn[1]; hn4.z = hn[2]; hn4.w = hn[3];
    cn4.x = cn[0]; cn4.y = cn[1]; cn4.z = cn[2]; cn4.w = cn[3];
    *(float4*)(out + (size_t)b * H + t * 4) = hn4;
    *(float4*)(out + BH + (size_t)b * H + t * 4) = cn4;
}

// ----------------------------------------------------------------- launcher
extern "C" void kernel_launch(void* const* d_in, const int* in_sizes, int n_in,
                              void* d_out, int out_size, void* d_ws, size_t ws_size,
                              hipStream_t stream) {
    const float* x     = (const float*)d_in[0];
    const float* h     = (const float*)d_in[1];
    const float* c     = (const float*)d_in[2];
    const float* w_ih  = (const float*)d_in[3];
    const float* w_hh  = (const float*)d_in[4];
    const float* b_ih  = (const float*)d_in[5];
    const float* gamma = (const float*)d_in[6];
    const float* beta  = (const float*)d_in[7];
    float* out = (float*)d_out;

    char* ws = (char*)d_ws;
    __hip_bfloat16* xb  = (__hip_bfloat16*)(ws);                      // 16 MB
    __hip_bfloat16* hb  = (__hip_bfloat16*)(ws + ((size_t)16 << 20)); // 16 MB
    __hip_bfloat16* wib = (__hip_bfloat16*)(ws + ((size_t)32 << 20)); //  8 MB
    __hip_bfloat16* whb = (__hip_bfloat16*)(ws + ((size_t)40 << 20)); //  8 MB
    __hip_bfloat16* pih = (__hip_bfloat16*)(ws + ((size_t)48 << 20)); // 64 MB
    __hip_bfloat16* phh = (__hip_bfloat16*)(ws + ((size_t)112 << 20));// 64 MB

    hipLaunchKernelGGL(cast_bf16_all, dim3(4096), dim3(256), 0, stream,
                       x, h, w_ih, w_hh, xb, hb, wib, whb);
    hipLaunchKernelGGL(gemm_bt128, dim3(4096 / 128, 8192 / 128, 2), dim3(256), 0, stream,
                       xb, hb, wib, whb, pih, phh);
    hipLaunchKernelGGL(lstm_fuse, dim3(8192), dim3(256), 0, stream,
                       pih, phh, c, b_ih, gamma, beta, out);
}

// Round 7
// 246.790 us; speedup vs baseline: 1.6006x; 1.0708x over previous
//
#include <hip/hip_runtime.h>
#include <hip/hip_bf16.h>

typedef __bf16 bf16x8_t __attribute__((ext_vector_type(8)));
typedef float f32x4_t __attribute__((ext_vector_type(4)));

static __device__ __forceinline__ float bf2f(unsigned short u) {
    union { unsigned int i; float f; } z; z.i = ((unsigned int)u) << 16; return z.f;
}

// ---------------------------------------------------------------- cast kernel
__global__ __launch_bounds__(256) void cast_bf16_all(
    const float* __restrict__ x, const float* __restrict__ h,
    const float* __restrict__ wi, const float* __restrict__ wh,
    __hip_bfloat16* __restrict__ xb, __hip_bfloat16* __restrict__ hb,
    __hip_bfloat16* __restrict__ wib, __hip_bfloat16* __restrict__ whb)
{
    const size_t CX = (size_t)8192 * 1024 / 8;
    const size_t CW = (size_t)4096 * 1024 / 8;
    const size_t TOT = CX * 2 + CW * 2;
    for (size_t cp = (size_t)blockIdx.x * blockDim.x + threadIdx.x; cp < TOT;
         cp += (size_t)gridDim.x * blockDim.x) {
        const float* src; __hip_bfloat16* dst; size_t off;
        if (cp < CX)            { src = x;  dst = xb;  off = cp; }
        else if (cp < 2 * CX)   { src = h;  dst = hb;  off = cp - CX; }
        else if (cp < 2*CX+CW)  { src = wi; dst = wib; off = cp - 2 * CX; }
        else                    { src = wh; dst = whb; off = cp - 2 * CX - CW; }
        const float4* s4 = (const float4*)src;
        float4 a = s4[off * 2], b = s4[off * 2 + 1];
        union { __hip_bfloat16 q[8]; uint4 u; } pk;
        pk.q[0] = __float2bfloat16(a.x); pk.q[1] = __float2bfloat16(a.y);
        pk.q[2] = __float2bfloat16(a.z); pk.q[3] = __float2bfloat16(a.w);
        pk.q[4] = __float2bfloat16(b.x); pk.q[5] = __float2bfloat16(b.y);
        pk.q[6] = __float2bfloat16(b.z); pk.q[7] = __float2bfloat16(b.w);
        ((uint4*)dst)[off] = pk.u;
    }
}

// ----------------------------------------------------- 256x256 pipelined GEMM
// P[m,n] = sum_k A[m,k] * W[n,k]   (A: MxK row-major, W: NxK row-major)
// M=8192, N=4096, K=1024.  BK=32, 4-buffer LDS ring, counted vmcnt, 8 waves.
__global__ __launch_bounds__(512, 2) void gemm_bt256(
    const __hip_bfloat16* __restrict__ Ax, const __hip_bfloat16* __restrict__ Ah,
    const __hip_bfloat16* __restrict__ Wi, const __hip_bfloat16* __restrict__ Wh,
    __hip_bfloat16* __restrict__ Pi, __hip_bfloat16* __restrict__ Ph)
{
    const int K = 1024, N = 4096, NT = 32;     // NT = K / 32
    const __hip_bfloat16* A; const __hip_bfloat16* W; __hip_bfloat16* P;
    if (blockIdx.z == 0) { A = Ax; W = Wi; P = Pi; }
    else                 { A = Ah; W = Wh; P = Ph; }
    const int n0 = blockIdx.x * 256, m0 = blockIdx.y * 256;

    // 4 buffers x (A 256x32 + W 256x32) bf16 = 4 x 32 KiB = 128 KiB
    __shared__ __align__(16) char smem[131072];

    const int t = threadIdx.x, w = t >> 6, l = t & 63;
    const int wm = w >> 2, wn = w & 3;          // 2 x 4 wave grid
    const int lrow = l & 15, s16 = l >> 4;      // fragment row-in-16 / 16B k-slot

    // ---- staging addresses (T2: pre-permuted global source, linear LDS dest)
    // slot = j*512 + t ; r = slot>>2 ; q = slot&3 ; srcSlot = (q - (r>>1)) & 3
    const __hip_bfloat16* srcA[2]; const __hip_bfloat16* srcB[2];
    int ldsoff[2];
    #pragma unroll
    for (int j = 0; j < 2; ++j) {
        const int slot = j * 512 + t;
        const int r = slot >> 2, q = slot & 3;
        const int srcSlot = (q - (r >> 1)) & 3;
        srcA[j] = A + (size_t)(m0 + r) * K + srcSlot * 8;
        srcB[j] = W + (size_t)(n0 + r) * K + srcSlot * 8;
        ldsoff[j] = slot * 16;
    }

    // ---- swizzled ds_read byte offsets (within a 16 KiB half-buffer)
    int offA[8], offB[4];
    #pragma unroll
    for (int mi = 0; mi < 8; ++mi) {
        const int r = wm * 128 + mi * 16 + lrow;
        const int q = (s16 + (r >> 1)) & 3;
        offA[mi] = r * 64 + q * 16;
    }
    #pragma unroll
    for (int ni = 0; ni < 4; ++ni) {
        const int r = wn * 64 + ni * 16 + lrow;
        const int q = (s16 + (r >> 1)) & 3;
        offB[ni] = r * 64 + q * 16;
    }

    f32x4_t acc[8][4];
    #pragma unroll
    for (int mi = 0; mi < 8; ++mi)
        #pragma unroll
        for (int ni = 0; ni < 4; ++ni)
            acc[mi][ni] = (f32x4_t){0.f, 0.f, 0.f, 0.f};

    auto STAGE = [&](int bi, int kt) {
        #pragma unroll
        for (int j = 0; j < 2; ++j) {
            __builtin_amdgcn_global_load_lds(
                (const __attribute__((address_space(1))) void*)(srcA[j] + kt * 32),
                (__attribute__((address_space(3))) void*)(smem + bi * 32768 + ldsoff[j]),
                16, 0, 0);
            __builtin_amdgcn_global_load_lds(
                (const __attribute__((address_space(1))) void*)(srcB[j] + kt * 32),
                (__attribute__((address_space(3))) void*)(smem + bi * 32768 + 16384 + ldsoff[j]),
                16, 0, 0);
        }
    };

    auto COMPUTE = [&](int bi) {
        const char* baseA = smem + bi * 32768;
        const char* baseB = baseA + 16384;
        bf16x8_t af[8], bfv[4];
        #pragma unroll
        for (int mi = 0; mi < 8; ++mi)
            af[mi] = *(const bf16x8_t*)(baseA + offA[mi]);
        #pragma unroll
        for (int ni = 0; ni < 4; ++ni)
            bfv[ni] = *(const bf16x8_t*)(baseB + offB[ni]);
        __builtin_amdgcn_s_setprio(1);
        #pragma unroll
        for (int mi = 0; mi < 8; ++mi)
            #pragma unroll
            for (int ni = 0; ni < 4; ++ni)
                acc[mi][ni] = __builtin_amdgcn_mfma_f32_16x16x32_bf16(
                    af[mi], bfv[ni], acc[mi][ni], 0, 0, 0);
        __builtin_amdgcn_s_setprio(0);
    };

    // ---- prologue: 3 tiles in flight
    STAGE(0, 0); STAGE(1, 1); STAGE(2, 2);
    asm volatile("s_waitcnt vmcnt(8)" ::: "memory");   // tile 0 landed
    __builtin_amdgcn_s_barrier();

    // ---- main loop: stage t+3, compute t, counted drain, one barrier/step
    for (int kt = 0; kt < NT - 3; ++kt) {
        STAGE((kt + 3) & 3, kt + 3);
        COMPUTE(kt & 3);
        asm volatile("s_waitcnt vmcnt(8)" ::: "memory");  // tile kt+1 landed
        __builtin_amdgcn_s_barrier();
    }
    // ---- epilogue: drain 8 -> 4 -> 0
    COMPUTE((NT - 3) & 3);
    asm volatile("s_waitcnt vmcnt(4)" ::: "memory");
    __builtin_amdgcn_s_barrier();
    COMPUTE((NT - 2) & 3);
    asm volatile("s_waitcnt vmcnt(0)" ::: "memory");
    __builtin_amdgcn_s_barrier();
    COMPUTE((NT - 1) & 3);

    // ---- C write (bf16), layout col=l&15, row=(l>>4)*4+q  (verified m89/m91)
    #pragma unroll
    for (int mi = 0; mi < 8; ++mi) {
        #pragma unroll
        for (int ni = 0; ni < 4; ++ni) {
            const int cc = n0 + wn * 64 + ni * 16 + (l & 15);
            #pragma unroll
            for (int q = 0; q < 4; ++q) {
                const int r = m0 + wm * 128 + mi * 16 + (l >> 4) * 4 + q;
                P[(size_t)r * N + cc] = __float2bfloat16(acc[mi][ni][q]);
            }
        }
    }
}

// ------------------------------------------------- fused LN + gates kernel
__global__ __launch_bounds__(256) void lstm_fuse(
    const __hip_bfloat16* __restrict__ pih, const __hip_bfloat16* __restrict__ phh,
    const float* __restrict__ c, const float* __restrict__ bih,
    const float* __restrict__ gamma, const float* __restrict__ beta,
    float* __restrict__ out)
{
    const int H = 1024;
    const size_t BH = (size_t)8192 * 1024;
    const int b = blockIdx.x, t = threadIdx.x;
    const int wid = t >> 6, lane = t & 63;

    __shared__ float red1[4][16];
    __shared__ float fin1[16];
    __shared__ float red2[8];

    const ushort* pi = (const ushort*)(pih + (size_t)b * 4096);
    const ushort* ph = (const ushort*)(phh + (size_t)b * 4096);

    ushort4 u[8];
    float sm[8], sq[8];
    #pragma unroll
    for (int s = 0; s < 8; ++s) {
        const ushort* src = ((s & 1) ? ph : pi) + (s >> 1) * H + t * 4;
        u[s] = *(const ushort4*)src;
        float a0 = bf2f(u[s].x), a1 = bf2f(u[s].y), a2 = bf2f(u[s].z), a3 = bf2f(u[s].w);
        sm[s] = a0 + a1 + a2 + a3;
        sq[s] = a0*a0 + a1*a1 + a2*a2 + a3*a3;
    }
    #pragma unroll
    for (int o = 32; o > 0; o >>= 1) {
        #pragma unroll
        for (int s = 0; s < 8; ++s) {
            sm[s] += __shfl_down(sm[s], o);
            sq[s] += __shfl_down(sq[s], o);
        }
    }
    if (lane == 0) {
        #pragma unroll
        for (int s = 0; s < 8; ++s) {
            red1[wid][s * 2]     = sm[s];
            red1[wid][s * 2 + 1] = sq[s];
        }
    }
    __syncthreads();
    if (t < 16) fin1[t] = red1[0][t] + red1[1][t] + red1[2][t] + red1[3][t];
    __syncthreads();

    float mu[8], rs[8];
    {
        float4 f0 = *(const float4*)&fin1[0],  f1 = *(const float4*)&fin1[4];
        float4 f2 = *(const float4*)&fin1[8],  f3 = *(const float4*)&fin1[12];
        float fv[16] = {f0.x,f0.y,f0.z,f0.w, f1.x,f1.y,f1.z,f1.w,
                        f2.x,f2.y,f2.z,f2.w, f3.x,f3.y,f3.z,f3.w};
        #pragma unroll
        for (int s = 0; s < 8; ++s) {
            mu[s] = fv[s * 2] * (1.f / H);
            rs[s] = rsqrtf(fv[s * 2 + 1] * (1.f / H) - mu[s] * mu[s] + 1e-5f);
        }
    }

    float n[4][4];
    #pragma unroll
    for (int g = 0; g < 4; ++g) {
        const int si = g * 2, sh = g * 2 + 1;
        float4 ga = *(const float4*)&gamma[si * H + t * 4];
        float4 ba = *(const float4*)&beta [si * H + t * 4];
        float4 gh = *(const float4*)&gamma[sh * H + t * 4];
        float4 bh = *(const float4*)&beta [sh * H + t * 4];
        float4 bi = *(const float4*)&bih  [g  * H + t * 4];
        const float gav[4] = {ga.x,ga.y,ga.z,ga.w}, bav[4] = {ba.x,ba.y,ba.z,ba.w};
        const float ghv[4] = {gh.x,gh.y,gh.z,gh.w}, bhv[4] = {bh.x,bh.y,bh.z,bh.w};
        const float biv[4] = {bi.x,bi.y,bi.z,bi.w};
        const ushort uiv[4] = {u[si].x, u[si].y, u[si].z, u[si].w};
        const ushort uhv[4] = {u[sh].x, u[sh].y, u[sh].z, u[sh].w};
        #pragma unroll
        for (int q = 0; q < 4; ++q) {
            float a_ = (bf2f(uiv[q]) - mu[si]) * rs[si] * gav[q] + bav[q];
            float h_ = (bf2f(uhv[q]) - mu[sh]) * rs[sh] * ghv[q] + bhv[q];
            n[g][q] = a_ + h_ + biv[q];
        }
    }

    float4 cv4 = *(const float4*)(c + (size_t)b * H + t * 4);
    const float cvv[4] = {cv4.x, cv4.y, cv4.z, cv4.w};
    float ov[4], cn[4];
    float s9 = 0.f, q9 = 0.f;
    #pragma unroll
    for (int q = 0; q < 4; ++q) {
        const float ig = 1.f / (1.f + __expf(-n[0][q]));
        const float fg = 1.f / (1.f + __expf(-n[1][q]));
        const float ag = tanhf(n[2][q]);
        const float og = 1.f / (1.f + __expf(-n[3][q]));
        cn[q] = fg * cvv[q] + ig * ag;
        ov[q] = og;
        s9 += cn[q]; q9 += cn[q] * cn[q];
    }
    #pragma unroll
    for (int o = 32; o > 0; o >>= 1) {
        s9 += __shfl_down(s9, o);
        q9 += __shfl_down(q9, o);
    }
    if (lane == 0) { red2[wid * 2] = s9; red2[wid * 2 + 1] = q9; }
    __syncthreads();
    const float S9 = red2[0] + red2[2] + red2[4] + red2[6];
    const float Q9 = red2[1] + red2[3] + red2[5] + red2[7];
    const float mu9 = S9 * (1.f / H);
    const float rs9 = rsqrtf(Q9 * (1.f / H) - mu9 * mu9 + 1e-5f);

    float4 g9 = *(const float4*)&gamma[8 * H + t * 4];
    float4 b9 = *(const float4*)&beta [8 * H + t * 4];
    const float g9v[4] = {g9.x,g9.y,g9.z,g9.w}, b9v[4] = {b9.x,b9.y,b9.z,b9.w};
    float4 hn4, cn4;
    float hn[4];
    #pragma unroll
    for (int q = 0; q < 4; ++q)
        hn[q] = ov[q] * tanhf((cn[q] - mu9) * rs9 * g9v[q] + b9v[q]);
    hn4.x = hn[0]; hn4.y = hn[1]; hn4.z = hn[2]; hn4.w = hn[3];
    cn4.x = cn[0]; cn4.y = cn[1]; cn4.z = cn[2]; cn4.w = cn[3];
    *(float4*)(out + (size_t)b * H + t * 4) = hn4;
    *(float4*)(out + BH + (size_t)b * H + t * 4) = cn4;
}

// ----------------------------------------------------------------- launcher
extern "C" void kernel_launch(void* const* d_in, const int* in_sizes, int n_in,
                              void* d_out, int out_size, void* d_ws, size_t ws_size,
                              hipStream_t stream) {
    const float* x     = (const float*)d_in[0];
    const float* h     = (const float*)d_in[1];
    const float* c     = (const float*)d_in[2];
    const float* w_ih  = (const float*)d_in[3];
    const float* w_hh  = (const float*)d_in[4];
    const float* b_ih  = (const float*)d_in[5];
    const float* gamma = (const float*)d_in[6];
    const float* beta  = (const float*)d_in[7];
    float* out = (float*)d_out;

    char* ws = (char*)d_ws;
    __hip_bfloat16* xb  = (__hip_bfloat16*)(ws);                      // 16 MB
    __hip_bfloat16* hb  = (__hip_bfloat16*)(ws + ((size_t)16 << 20)); // 16 MB
    __hip_bfloat16* wib = (__hip_bfloat16*)(ws + ((size_t)32 << 20)); //  8 MB
    __hip_bfloat16* whb = (__hip_bfloat16*)(ws + ((size_t)40 << 20)); //  8 MB
    __hip_bfloat16* pih = (__hip_bfloat16*)(ws + ((size_t)48 << 20)); // 64 MB
    __hip_bfloat16* phh = (__hip_bfloat16*)(ws + ((size_t)112 << 20));// 64 MB

    hipLaunchKernelGGL(cast_bf16_all, dim3(4096), dim3(256), 0, stream,
                       x, h, w_ih, w_hh, xb, hb, wib, whb);
    hipLaunchKernelGGL(gemm_bt256, dim3(4096 / 256, 8192 / 256, 2), dim3(512), 0, stream,
                       xb, hb, wib, whb, pih, phh);
    hipLaunchKernelGGL(lstm_fuse, dim3(8192), dim3(256), 0, stream,
                       pih, phh, c, b_ih, gamma, beta, out);
}

// Round 8
// 244.007 us; speedup vs baseline: 1.6189x; 1.0114x over previous
//
#include <hip/hip_runtime.h>
#include <hip/hip_bf16.h>

typedef __bf16 bf16x8_t __attribute__((ext_vector_type(8)));
typedef float f32x4_t __attribute__((ext_vector_type(4)));

static __device__ __forceinline__ float bf2f(unsigned short u) {
    union { unsigned int i; float f; } z; z.i = ((unsigned int)u) << 16; return z.f;
}

// ---------------------------------------------------------------- cast kernel
__global__ __launch_bounds__(256) void cast_bf16_all(
    const float* __restrict__ x, const float* __restrict__ h,
    const float* __restrict__ wi, const float* __restrict__ wh,
    __hip_bfloat16* __restrict__ xb, __hip_bfloat16* __restrict__ hb,
    __hip_bfloat16* __restrict__ wib, __hip_bfloat16* __restrict__ whb)
{
    const size_t CX = (size_t)8192 * 1024 / 8;
    const size_t CW = (size_t)4096 * 1024 / 8;
    const size_t TOT = CX * 2 + CW * 2;
    for (size_t cp = (size_t)blockIdx.x * blockDim.x + threadIdx.x; cp < TOT;
         cp += (size_t)gridDim.x * blockDim.x) {
        const float* src; __hip_bfloat16* dst; size_t off;
        if (cp < CX)            { src = x;  dst = xb;  off = cp; }
        else if (cp < 2 * CX)   { src = h;  dst = hb;  off = cp - CX; }
        else if (cp < 2*CX+CW)  { src = wi; dst = wib; off = cp - 2 * CX; }
        else                    { src = wh; dst = whb; off = cp - 2 * CX - CW; }
        const float4* s4 = (const float4*)src;
        float4 a = s4[off * 2], b = s4[off * 2 + 1];
        union { __hip_bfloat16 q[8]; uint4 u; } pk;
        pk.q[0] = __float2bfloat16(a.x); pk.q[1] = __float2bfloat16(a.y);
        pk.q[2] = __float2bfloat16(a.z); pk.q[3] = __float2bfloat16(a.w);
        pk.q[4] = __float2bfloat16(b.x); pk.q[5] = __float2bfloat16(b.y);
        pk.q[6] = __float2bfloat16(b.z); pk.q[7] = __float2bfloat16(b.w);
        ((uint4*)dst)[off] = pk.u;
    }
}

// ----------------------------------------------------- 256x256 pipelined GEMM
// P[m,n] = sum_k A[m,k] * W[n,k]   (A: MxK row-major, W: NxK row-major)
// M=8192, N=4096, K=1024.  BK=32, ring-4 LDS, counted vmcnt, 8 waves,
// 2 phases per K-step (read-cluster || stage || barrier || 16-MFMA cluster).
__global__ __launch_bounds__(512, 2) void gemm_bt256(
    const __hip_bfloat16* __restrict__ Ax, const __hip_bfloat16* __restrict__ Ah,
    const __hip_bfloat16* __restrict__ Wi, const __hip_bfloat16* __restrict__ Wh,
    __hip_bfloat16* __restrict__ Pi, __hip_bfloat16* __restrict__ Ph)
{
    const int K = 1024, N = 4096, NT = 32;     // NT = K / 32
    const __hip_bfloat16* A; const __hip_bfloat16* W; __hip_bfloat16* P;
    if (blockIdx.z == 0) { A = Ax; W = Wi; P = Pi; }
    else                 { A = Ah; W = Wh; P = Ph; }
    const int n0 = blockIdx.x * 256, m0 = blockIdx.y * 256;

    // 4 buffers x (A 256x32 + W 256x32) bf16 = 4 x 32 KiB = 128 KiB
    __shared__ __align__(16) char smem[131072];

    const int t = threadIdx.x, w = t >> 6, l = t & 63;
    const int wm = w >> 2, wn = w & 3;          // 2 x 4 wave grid
    const int lrow = l & 15, s16 = l >> 4;      // fragment row-in-16 / 16B k-slot

    // ---- staging addresses (pre-permuted global source, linear LDS dest)
    const __hip_bfloat16* srcA[2]; const __hip_bfloat16* srcB[2];
    int ldsoff[2];
    #pragma unroll
    for (int j = 0; j < 2; ++j) {
        const int slot = j * 512 + t;
        const int r = slot >> 2, q = slot & 3;
        const int srcSlot = (q - (r >> 1)) & 3;
        srcA[j] = A + (size_t)(m0 + r) * K + srcSlot * 8;
        srcB[j] = W + (size_t)(n0 + r) * K + srcSlot * 8;
        ldsoff[j] = slot * 16;
    }

    // ---- swizzled ds_read byte offsets (within a 16 KiB half-buffer)
    int offA[8], offB[4];
    #pragma unroll
    for (int mi = 0; mi < 8; ++mi) {
        const int r = wm * 128 + mi * 16 + lrow;
        const int q = (s16 + (r >> 1)) & 3;
        offA[mi] = r * 64 + q * 16;
    }
    #pragma unroll
    for (int ni = 0; ni < 4; ++ni) {
        const int r = wn * 64 + ni * 16 + lrow;
        const int q = (s16 + (r >> 1)) & 3;
        offB[ni] = r * 64 + q * 16;
    }

    f32x4_t acc[8][4];
    #pragma unroll
    for (int mi = 0; mi < 8; ++mi)
        #pragma unroll
        for (int ni = 0; ni < 4; ++ni)
            acc[mi][ni] = (f32x4_t){0.f, 0.f, 0.f, 0.f};

    auto STAGE_J = [&](int bi, int kt, int j) {
        __builtin_amdgcn_global_load_lds(
            (const __attribute__((address_space(1))) void*)(srcA[j] + kt * 32),
            (__attribute__((address_space(3))) void*)(smem + bi * 32768 + ldsoff[j]),
            16, 0, 0);
        __builtin_amdgcn_global_load_lds(
            (const __attribute__((address_space(1))) void*)(srcB[j] + kt * 32),
            (__attribute__((address_space(3))) void*)(smem + bi * 32768 + 16384 + ldsoff[j]),
            16, 0, 0);
    };

    auto READ_A03_B = [&](int bi, bf16x8_t* a4, bf16x8_t* b4) {
        const char* baseA = smem + bi * 32768;
        const char* baseB = baseA + 16384;
        #pragma unroll
        for (int mi = 0; mi < 4; ++mi) a4[mi] = *(const bf16x8_t*)(baseA + offA[mi]);
        #pragma unroll
        for (int ni = 0; ni < 4; ++ni) b4[ni] = *(const bf16x8_t*)(baseB + offB[ni]);
    };
    auto READ_A47 = [&](int bi, bf16x8_t* a4) {
        const char* baseA = smem + bi * 32768;
        #pragma unroll
        for (int mi = 0; mi < 4; ++mi) a4[mi] = *(const bf16x8_t*)(baseA + offA[4 + mi]);
    };
    auto MFMA16 = [&](const bf16x8_t* a4, const bf16x8_t* b4, int mb) {
        __builtin_amdgcn_s_setprio(1);
        #pragma unroll
        for (int mi = 0; mi < 4; ++mi)
            #pragma unroll
            for (int ni = 0; ni < 4; ++ni)
                acc[mb + mi][ni] = __builtin_amdgcn_mfma_f32_16x16x32_bf16(
                    a4[mi], b4[ni], acc[mb + mi][ni], 0, 0, 0);
        __builtin_amdgcn_s_setprio(0);
    };

    // ---- prologue: 3 tiles in flight (12 loads); tile 0 = oldest 4
    #pragma unroll
    for (int p = 0; p < 3; ++p) { STAGE_J(p, p, 0); STAGE_J(p, p, 1); }
    asm volatile("s_waitcnt vmcnt(8)" ::: "memory");
    __builtin_amdgcn_s_barrier();

    // ---- main loop: 2 phases per K-step
    for (int kt = 0; kt < NT - 3; ++kt) {
        const int bi = kt & 3, bn = (kt + 3) & 3;
        bf16x8_t a0[4], a1[4], b[4];
        // Phase A
        READ_A03_B(bi, a0, b);
        STAGE_J(bn, kt + 3, 0);
        __builtin_amdgcn_s_barrier();
        MFMA16(a0, b, 0);
        // Phase B
        READ_A47(bi, a1);
        STAGE_J(bn, kt + 3, 1);
        asm volatile("s_waitcnt vmcnt(8)" ::: "memory");  // tile kt+1 landed
        __builtin_amdgcn_s_barrier();
        MFMA16(a1, b, 4);
    }

    // ---- epilogue: steps NT-3 / NT-2 / NT-1, drains 4 -> 0
    {
        const int bi = (NT - 3) & 3;
        bf16x8_t a0[4], a1[4], b[4];
        READ_A03_B(bi, a0, b);
        __builtin_amdgcn_s_barrier();
        MFMA16(a0, b, 0);
        READ_A47(bi, a1);
        asm volatile("s_waitcnt vmcnt(4)" ::: "memory");
        __builtin_amdgcn_s_barrier();
        MFMA16(a1, b, 4);
    }
    {
        const int bi = (NT - 2) & 3;
        bf16x8_t a0[4], a1[4], b[4];
        READ_A03_B(bi, a0, b);
        __builtin_amdgcn_s_barrier();
        MFMA16(a0, b, 0);
        READ_A47(bi, a1);
        asm volatile("s_waitcnt vmcnt(0)" ::: "memory");
        __builtin_amdgcn_s_barrier();
        MFMA16(a1, b, 4);
    }
    {
        const int bi = (NT - 1) & 3;
        bf16x8_t a0[4], a1[4], b[4];
        READ_A03_B(bi, a0, b);
        MFMA16(a0, b, 0);
        READ_A47(bi, a1);
        MFMA16(a1, b, 4);
    }

    // ---- C write (bf16), layout col=l&15, row=(l>>4)*4+q  (verified m89/m91)
    #pragma unroll
    for (int mi = 0; mi < 8; ++mi) {
        #pragma unroll
        for (int ni = 0; ni < 4; ++ni) {
            const int cc = n0 + wn * 64 + ni * 16 + (l & 15);
            #pragma unroll
            for (int q = 0; q < 4; ++q) {
                const int r = m0 + wm * 128 + mi * 16 + (l >> 4) * 4 + q;
                P[(size_t)r * N + cc] = __float2bfloat16(acc[mi][ni][q]);
            }
        }
    }
}

// ------------------------------------------------- fused LN + gates kernel
__global__ __launch_bounds__(256) void lstm_fuse(
    const __hip_bfloat16* __restrict__ pih, const __hip_bfloat16* __restrict__ phh,
    const float* __restrict__ c, const float* __restrict__ bih,
    const float* __restrict__ gamma, const float* __restrict__ beta,
    float* __restrict__ out)
{
    const int H = 1024;
    const size_t BH = (size_t)8192 * 1024;
    const int b = blockIdx.x, t = threadIdx.x;
    const int wid = t >> 6, lane = t & 63;

    __shared__ float red1[4][16];
    __shared__ float fin1[16];
    __shared__ float red2[8];

    const ushort* pi = (const ushort*)(pih + (size_t)b * 4096);
    const ushort* ph = (const ushort*)(phh + (size_t)b * 4096);

    ushort4 u[8];
    float sm[8], sq[8];
    #pragma unroll
    for (int s = 0; s < 8; ++s) {
        const ushort* src = ((s & 1) ? ph : pi) + (s >> 1) * H + t * 4;
        u[s] = *(const ushort4*)src;
        float a0 = bf2f(u[s].x), a1 = bf2f(u[s].y), a2 = bf2f(u[s].z), a3 = bf2f(u[s].w);
        sm[s] = a0 + a1 + a2 + a3;
        sq[s] = a0*a0 + a1*a1 + a2*a2 + a3*a3;
    }
    #pragma unroll
    for (int o = 32; o > 0; o >>= 1) {
        #pragma unroll
        for (int s = 0; s < 8; ++s) {
            sm[s] += __shfl_down(sm[s], o);
            sq[s] += __shfl_down(sq[s], o);
        }
    }
    if (lane == 0) {
        #pragma unroll
        for (int s = 0; s < 8; ++s) {
            red1[wid][s * 2]     = sm[s];
            red1[wid][s * 2 + 1] = sq[s];
        }
    }
    __syncthreads();
    if (t < 16) fin1[t] = red1[0][t] + red1[1][t] + red1[2][t] + red1[3][t];
    __syncthreads();

    float mu[8], rs[8];
    {
        float4 f0 = *(const float4*)&fin1[0],  f1 = *(const float4*)&fin1[4];
        float4 f2 = *(const float4*)&fin1[8],  f3 = *(const float4*)&fin1[12];
        float fv[16] = {f0.x,f0.y,f0.z,f0.w, f1.x,f1.y,f1.z,f1.w,
                        f2.x,f2.y,f2.z,f2.w, f3.x,f3.y,f3.z,f3.w};
        #pragma unroll
        for (int s = 0; s < 8; ++s) {
            mu[s] = fv[s * 2] * (1.f / H);
            rs[s] = rsqrtf(fv[s * 2 + 1] * (1.f / H) - mu[s] * mu[s] + 1e-5f);
        }
    }

    float n[4][4];
    #pragma unroll
    for (int g = 0; g < 4; ++g) {
        const int si = g * 2, sh = g * 2 + 1;
        float4 ga = *(const float4*)&gamma[si * H + t * 4];
        float4 ba = *(const float4*)&beta [si * H + t * 4];
        float4 gh = *(const float4*)&gamma[sh * H + t * 4];
        float4 bh = *(const float4*)&beta [sh * H + t * 4];
        float4 bi = *(const float4*)&bih  [g  * H + t * 4];
        const float gav[4] = {ga.x,ga.y,ga.z,ga.w}, bav[4] = {ba.x,ba.y,ba.z,ba.w};
        const float ghv[4] = {gh.x,gh.y,gh.z,gh.w}, bhv[4] = {bh.x,bh.y,bh.z,bh.w};
        const float biv[4] = {bi.x,bi.y,bi.z,bi.w};
        const ushort uiv[4] = {u[si].x, u[si].y, u[si].z, u[si].w};
        const ushort uhv[4] = {u[sh].x, u[sh].y, u[sh].z, u[sh].w};
        #pragma unroll
        for (int q = 0; q < 4; ++q) {
            float a_ = (bf2f(uiv[q]) - mu[si]) * rs[si] * gav[q] + bav[q];
            float h_ = (bf2f(uhv[q]) - mu[sh]) * rs[sh] * ghv[q] + bhv[q];
            n[g][q] = a_ + h_ + biv[q];
        }
    }

    float4 cv4 = *(const float4*)(c + (size_t)b * H + t * 4);
    const float cvv[4] = {cv4.x, cv4.y, cv4.z, cv4.w};
    float ov[4], cn[4];
    float s9 = 0.f, q9 = 0.f;
    #pragma unroll
    for (int q = 0; q < 4; ++q) {
        const float ig = 1.f / (1.f + __expf(-n[0][q]));
        const float fg = 1.f / (1.f + __expf(-n[1][q]));
        const float ag = tanhf(n[2][q]);
        const float og = 1.f / (1.f + __expf(-n[3][q]));
        cn[q] = fg * cvv[q] + ig * ag;
        ov[q] = og;
        s9 += cn[q]; q9 += cn[q] * cn[q];
    }
    #pragma unroll
    for (int o = 32; o > 0; o >>= 1) {
        s9 += __shfl_down(s9, o);
        q9 += __shfl_down(q9, o);
    }
    if (lane == 0) { red2[wid * 2] = s9; red2[wid * 2 + 1] = q9; }
    __syncthreads();
    const float S9 = red2[0] + red2[2] + red2[4] + red2[6];
    const float Q9 = red2[1] + red2[3] + red2[5] + red2[7];
    const float mu9 = S9 * (1.f / H);
    const float rs9 = rsqrtf(Q9 * (1.f / H) - mu9 * mu9 + 1e-5f);

    float4 g9 = *(const float4*)&gamma[8 * H + t * 4];
    float4 b9 = *(const float4*)&beta [8 * H + t * 4];
    const float g9v[4] = {g9.x,g9.y,g9.z,g9.w}, b9v[4] = {b9.x,b9.y,b9.z,b9.w};
    float4 hn4, cn4;
    float hn[4];
    #pragma unroll
    for (int q = 0; q < 4; ++q)
        hn[q] = ov[q] * tanhf((cn[q] - mu9) * rs9 * g9v[q] + b9v[q]);
    hn4.x = hn[0]; hn4.y = hn[1]; hn4.z = hn[2]; hn4.w = hn[3];
    cn4.x = cn[0]; cn4.y = cn[1]; cn4.z = cn[2]; cn4.w = cn[3];
    *(float4*)(out + (size_t)b * H + t * 4) = hn4;
    *(float4*)(out + BH + (size_t)b * H + t * 4) = cn4;
}

// ----------------------------------------------------------------- launcher
extern "C" void kernel_launch(void* const* d_in, const int* in_sizes, int n_in,
                              void* d_out, int out_size, void* d_ws, size_t ws_size,
                              hipStream_t stream) {
    const float* x     = (const float*)d_in[0];
    const float* h     = (const float*)d_in[1];
    const float* c     = (const float*)d_in[2];
    const float* w_ih  = (const float*)d_in[3];
    const float* w_hh  = (const float*)d_in[4];
    const float* b_ih  = (const float*)d_in[5];
    const float* gamma = (const float*)d_in[6];
    const float* beta  = (const float*)d_in[7];
    float* out = (float*)d_out;

    char* ws = (char*)d_ws;
    __hip_bfloat16* xb  = (__hip_bfloat16*)(ws);                      // 16 MB
    __hip_bfloat16* hb  = (__hip_bfloat16*)(ws + ((size_t)16 << 20)); // 16 MB
    __hip_bfloat16* wib = (__hip_bfloat16*)(ws + ((size_t)32 << 20)); //  8 MB
    __hip_bfloat16* whb = (__hip_bfloat16*)(ws + ((size_t)40 << 20)); //  8 MB
    __hip_bfloat16* pih = (__hip_bfloat16*)(ws + ((size_t)48 << 20)); // 64 MB
    __hip_bfloat16* phh = (__hip_bfloat16*)(ws + ((size_t)112 << 20));// 64 MB

    hipLaunchKernelGGL(cast_bf16_all, dim3(4096), dim3(256), 0, stream,
                       x, h, w_ih, w_hh, xb, hb, wib, whb);
    hipLaunchKernelGGL(gemm_bt256, dim3(4096 / 256, 8192 / 256, 2), dim3(512), 0, stream,
                       xb, hb, wib, whb, pih, phh);
    hipLaunchKernelGGL(lstm_fuse, dim3(8192), dim3(256), 0, stream,
                       pih, phh, c, b_ih, gamma, beta, out);
}